// Round 1
// baseline (16826.518 us; speedup 1.0000x reference)
//
#include <hip/hip_runtime.h>
#include <stdint.h>

// ---------------------------------------------------------------------------
// RNN scan: out = (states[B,T,NH], last[B,NH]), fp32.
// Phase 1: u = tanh(x @ Wi^T + bi) written straight into the states region.
// Phase 2: persistent kernel; 8 independent batch-groups x 16 h-slice WGs.
//          State history lives in d_out itself; cross-WG traffic is
//          coherence-point atomics; per-WG Wh slice resident in LDS as
//          pre-swizzled MFMA fragments.
// ---------------------------------------------------------------------------

typedef _Float16 half8 __attribute__((ext_vector_type(8)));
typedef float    f32x4 __attribute__((ext_vector_type(4)));

#define T_STEPS 1024
#define NHID    512
#define NIN     128
#define NBATCH  64
#define STATES_ELEMS (NBATCH * T_STEPS * NHID)  // 33554432

__device__ __forceinline__ float tanh_fast(float x) {
  // tanh(x) = 1 - 2/(exp(2x)+1); exp overflow/underflow saturate correctly.
  float e = __expf(2.0f * x);
  return 1.0f - 2.0f * __builtin_amdgcn_rcpf(e + 1.0f);
}

// ---------------------------------------------------------------------------
__global__ void init_flags(uint32_t* flags) {
  if (threadIdx.x < 128) flags[threadIdx.x] = 0;
}

// ---------------------------------------------------------------------------
// Phase 1: M=65536 (b*T+t), N=512 (h), K=128. 64x64 tile per WG (4 waves,
// each wave: 16 M-rows x 64 N via 4 N-tiles, mfma_f32_16x16x32_f16).
// A-frag: m=lane&15, k=quad*8+j. B-frag: n=lane&15, k=quad*8+j.
// D: col=lane&15, row=quad*4+reg.
__global__ __launch_bounds__(256) void phase1_gemm(const float* __restrict__ x,
                                                   const float* __restrict__ Wi,
                                                   const float* __restrict__ bi,
                                                   float* __restrict__ out) {
  const int tid  = threadIdx.x;
  const int wid  = tid >> 6;
  const int lane = tid & 63;
  const int quad = lane >> 4;
  const int mcol = lane & 15;
  const int r0 = blockIdx.x * 64 + wid * 16;
  const int h0 = blockIdx.y * 64;

  f32x4 acc[4] = {};
#pragma unroll
  for (int kk = 0; kk < 4; kk++) {
    const int k = kk * 32 + quad * 8;
    const f32x4* ap = (const f32x4*)(x + (size_t)(r0 + mcol) * NIN + k);
    f32x4 alo = ap[0], ahi = ap[1];
    half8 a;
#pragma unroll
    for (int j = 0; j < 4; j++) { a[j] = (_Float16)alo[j]; a[4 + j] = (_Float16)ahi[j]; }
#pragma unroll
    for (int nt = 0; nt < 4; nt++) {
      const f32x4* bp = (const f32x4*)(Wi + (size_t)(h0 + nt * 16 + mcol) * NIN + k);
      f32x4 blo = bp[0], bhi = bp[1];
      half8 b;
#pragma unroll
      for (int j = 0; j < 4; j++) { b[j] = (_Float16)blo[j]; b[4 + j] = (_Float16)bhi[j]; }
      acc[nt] = __builtin_amdgcn_mfma_f32_16x16x32_f16(a, b, acc[nt], 0, 0, 0);
    }
  }
#pragma unroll
  for (int nt = 0; nt < 4; nt++) {
    const int h = h0 + nt * 16 + mcol;
    const float bib = bi[h];
#pragma unroll
    for (int rr = 0; rr < 4; rr++) {
      const int r = r0 + quad * 4 + rr;
      out[(size_t)r * NHID + h] = tanh_fast(acc[nt][rr] + bib);
    }
  }
}

// ---------------------------------------------------------------------------
// Phase 2: persistent scan. Grid = 128 WGs x 256 threads.
//   group g = wg>>4 owns batches [8g, 8g+8); slice w = wg&15 owns h [32w, 32w+32).
//   Waves: wid=(nt,kh): nt=wid&1 selects 16-wide N-tile, kh=wid>>1 selects K half.
//   LDS fragment order: chunk index = kk*64 + quad*16 + row  (16B half8 chunks)
//   so the MFMA inner loop is AF[kk*64+lane] / WhF[(nt*16+kk)*64+lane]:
//   consecutive lanes -> consecutive 16B, conflict-free ds_read_b128.
__global__ __launch_bounds__(256) void phase2_scan(const float* __restrict__ Wh,
                                                   const float* __restrict__ bh,
                                                   float* out, uint32_t* flags) {
  const int tid  = threadIdx.x;
  const int wid  = tid >> 6;
  const int lane = tid & 63;
  const int quad = lane >> 4;
  const int col  = lane & 15;
  const int wg = blockIdx.x;
  const int g  = wg >> 4;
  const int w  = wg & 15;
  const int b0 = g * 8;
  const int h0 = w * 32;

  __shared__ half8 WhF[2 * 16 * 64];  // 32 KB: Wh slice, fragment order
  __shared__ half8 AF[16 * 64];       // 16 KB: state (rows 8..15 stay zero)
  __shared__ f32x4 RED[2 * 64];       // 2 KB : K-half partial sums

  // ---- preload Wh[h0..h0+32) as f16 fragments -----------------------------
  {
    const int lh = tid >> 3;          // 0..31 local h row
    const int k0 = (tid & 7) * 64;    // 8 threads cover K=512
    const int nt_ = lh >> 4, n_ = lh & 15;
    const float* src = Wh + (size_t)(h0 + lh) * NHID + k0;
#pragma unroll
    for (int c = 0; c < 8; c++) {
      const int k = k0 + c * 8;
      const f32x4* p = (const f32x4*)(src + c * 8);
      f32x4 lo = p[0], hi = p[1];
      half8 hb;
#pragma unroll
      for (int j = 0; j < 4; j++) { hb[j] = (_Float16)lo[j]; hb[4 + j] = (_Float16)hi[j]; }
      WhF[(nt_ * 16 + (k >> 5)) * 64 + ((k >> 3) & 3) * 16 + n_] = hb;
    }
    half8 z = {0, 0, 0, 0, 0, 0, 0, 0};
    for (int i = tid; i < 16 * 64; i += 256) AF[i] = z;  // zero => t=0 state, rows 8..15
  }
  __syncthreads();

  const int nt = wid & 1;
  const int kh = wid >> 1;
  float bhv = 0.0f;
  if (wid < 2) bhv = bh[h0 + nt * 16 + col];
  uint32_t* const myflag = flags + wg;
  uint32_t* const gflags = flags + g * 16;

  for (int t = 0; t < T_STEPS; t++) {
    // u prefetch (independent of state; off the critical path)
    float uv[4] = {0, 0, 0, 0};
    if (wid < 2 && quad < 2) {
#pragma unroll
      for (int rr = 0; rr < 4; rr++) {
        const int row = quad * 4 + rr;
        uv[rr] = out[((size_t)(b0 + row) * T_STEPS + t) * NHID + h0 + nt * 16 + col];
      }
    }

    if (t > 0) {
      // wait until all 16 group peers have published step t-1
      if (tid < 16) {
        while (__hip_atomic_load(gflags + tid, __ATOMIC_ACQUIRE,
                                 __HIP_MEMORY_SCOPE_AGENT) < (uint32_t)t) {
          __builtin_amdgcn_s_sleep(1);
        }
      }
      __syncthreads();
      // stage state s_{t-1}[8 x 512] fp32 -> f16 fragments in AF
      const int m   = tid >> 5;          // batch row 0..7
      const int k0s = (tid & 31) * 16;   // 16 consecutive k per thread
      float* sp = out + ((size_t)(b0 + m) * T_STEPS + (t - 1)) * NHID + k0s;
      float svv[16];
#pragma unroll
      for (int i = 0; i < 16; i++)
        svv[i] = __hip_atomic_load(sp + i, __ATOMIC_RELAXED, __HIP_MEMORY_SCOPE_AGENT);
#pragma unroll
      for (int c = 0; c < 2; c++) {
        half8 hc;
#pragma unroll
        for (int j = 0; j < 8; j++) hc[j] = (_Float16)svv[c * 8 + j];
        const int k = k0s + c * 8;
        AF[(k >> 5) * 64 + ((k >> 3) & 3) * 16 + m] = hc;
      }
    }
    __syncthreads();

    // C[16x16] per wave, K half per wave pair
    f32x4 acc = {0, 0, 0, 0};
#pragma unroll
    for (int i = 0; i < 8; i++) {
      const int kk = kh * 8 + i;
      half8 a = AF[kk * 64 + lane];
      half8 b = WhF[(nt * 16 + kk) * 64 + lane];
      acc = __builtin_amdgcn_mfma_f32_16x16x32_f16(a, b, acc, 0, 0, 0);
    }
    if (kh == 1) RED[nt * 64 + lane] = acc;
    __syncthreads();

    if (wid < 2) {
      acc += RED[nt * 64 + lane];
      if (quad < 2) {  // valid batch rows 0..7
#pragma unroll
        for (int rr = 0; rr < 4; rr++) {
          const int row = quad * 4 + rr;
          const float s = uv[rr] + tanh_fast(acc[rr] + bhv);
          const size_t oi = ((size_t)(b0 + row) * T_STEPS + t) * NHID + h0 + nt * 16 + col;
          __hip_atomic_store(out + oi, s, __ATOMIC_RELAXED, __HIP_MEMORY_SCOPE_AGENT);
          if (t == T_STEPS - 1)
            out[(size_t)STATES_ELEMS + (size_t)(b0 + row) * NHID + h0 + nt * 16 + col] = s;
        }
      }
    }
    __threadfence();      // drain write-through stores to coherence point
    __syncthreads();      // all threads' data globally visible
    if (tid == 0)
      __hip_atomic_store(myflag, (uint32_t)(t + 1), __ATOMIC_RELEASE,
                         __HIP_MEMORY_SCOPE_AGENT);
  }
}

// ---------------------------------------------------------------------------
extern "C" void kernel_launch(void* const* d_in, const int* in_sizes, int n_in,
                              void* d_out, int out_size, void* d_ws, size_t ws_size,
                              hipStream_t stream) {
  const float* x  = (const float*)d_in[0];
  const float* Wi = (const float*)d_in[1];
  const float* bi = (const float*)d_in[2];
  const float* Wh = (const float*)d_in[3];
  const float* bh = (const float*)d_in[4];
  float* out = (float*)d_out;
  uint32_t* flags = (uint32_t*)d_ws;  // 128 x u32, re-zeroed every launch

  hipLaunchKernelGGL(init_flags, dim3(1), dim3(128), 0, stream, flags);
  hipLaunchKernelGGL(phase1_gemm, dim3(1024, 8), dim3(256), 0, stream, x, Wi, bi, out);
  hipLaunchKernelGGL(phase2_scan, dim3(128), dim3(256), 0, stream, Wh, bh, out, flags);
}

// Round 2
// 4529.368 us; speedup vs baseline: 3.7150x; 3.7150x over previous
//
#include <hip/hip_runtime.h>
#include <stdint.h>

// ---------------------------------------------------------------------------
// RNN scan: out = (states[B,T,NH], last[B,NH]), fp32.
// Phase 1: u = tanh(x @ Wi^T + bi) written straight into the states region.
// Phase 2: persistent kernel; 8 independent batch-groups x 16 h-slice WGs.
//          State history lives in d_out itself; ALL cross-WG traffic is
//          relaxed agent-scope atomics (hardware-routed to the device
//          coherence point) — no acquire/release, so no buffer_inv /
//          buffer_wbl2 L2-maintenance storms. Ordering: stores ->
//          s_waitcnt vmcnt(0) -> s_barrier -> flag store.
// ---------------------------------------------------------------------------

typedef _Float16 half8 __attribute__((ext_vector_type(8)));
typedef float    f32x4 __attribute__((ext_vector_type(4)));

#define T_STEPS 1024
#define NHID    512
#define NIN     128
#define NBATCH  64
#define STATES_ELEMS (NBATCH * T_STEPS * NHID)  // 33554432

__device__ __forceinline__ float tanh_fast(float x) {
  float e = __expf(2.0f * x);
  return 1.0f - 2.0f * __builtin_amdgcn_rcpf(e + 1.0f);
}

// ---------------------------------------------------------------------------
__global__ void init_flags(uint32_t* flags) {
  if (threadIdx.x < 128) flags[threadIdx.x] = 0;
}

// ---------------------------------------------------------------------------
// Phase 1: M=65536 (b*T+t), N=512 (h), K=128. 64x64 tile per WG.
__global__ __launch_bounds__(256) void phase1_gemm(const float* __restrict__ x,
                                                   const float* __restrict__ Wi,
                                                   const float* __restrict__ bi,
                                                   float* __restrict__ out) {
  const int tid  = threadIdx.x;
  const int wid  = tid >> 6;
  const int lane = tid & 63;
  const int quad = lane >> 4;
  const int mcol = lane & 15;
  const int r0 = blockIdx.x * 64 + wid * 16;
  const int h0 = blockIdx.y * 64;

  f32x4 acc[4] = {};
#pragma unroll
  for (int kk = 0; kk < 4; kk++) {
    const int k = kk * 32 + quad * 8;
    const f32x4* ap = (const f32x4*)(x + (size_t)(r0 + mcol) * NIN + k);
    f32x4 alo = ap[0], ahi = ap[1];
    half8 a;
#pragma unroll
    for (int j = 0; j < 4; j++) { a[j] = (_Float16)alo[j]; a[4 + j] = (_Float16)ahi[j]; }
#pragma unroll
    for (int nt = 0; nt < 4; nt++) {
      const f32x4* bp = (const f32x4*)(Wi + (size_t)(h0 + nt * 16 + mcol) * NIN + k);
      f32x4 blo = bp[0], bhi = bp[1];
      half8 b;
#pragma unroll
      for (int j = 0; j < 4; j++) { b[j] = (_Float16)blo[j]; b[4 + j] = (_Float16)bhi[j]; }
      acc[nt] = __builtin_amdgcn_mfma_f32_16x16x32_f16(a, b, acc[nt], 0, 0, 0);
    }
  }
#pragma unroll
  for (int nt = 0; nt < 4; nt++) {
    const int h = h0 + nt * 16 + mcol;
    const float bib = bi[h];
#pragma unroll
    for (int rr = 0; rr < 4; rr++) {
      const int r = r0 + quad * 4 + rr;
      out[(size_t)r * NHID + h] = tanh_fast(acc[nt][rr] + bib);
    }
  }
}

// ---------------------------------------------------------------------------
// Phase 2: persistent scan. Grid = 128 WGs x 256 threads.
//   group g = wg>>4 owns batches [8g, 8g+8); slice w = wg&15 owns h [32w, 32w+32).
__global__ __launch_bounds__(256) void phase2_scan(const float* __restrict__ Wh,
                                                   const float* __restrict__ bh,
                                                   float* out, uint32_t* flags) {
  const int tid  = threadIdx.x;
  const int wid  = tid >> 6;
  const int lane = tid & 63;
  const int quad = lane >> 4;
  const int col  = lane & 15;
  const int wg = blockIdx.x;
  const int g  = wg >> 4;
  const int w  = wg & 15;
  const int b0 = g * 8;
  const int h0 = w * 32;

  __shared__ half8 WhF[2 * 16 * 64];  // 32 KB: Wh slice, fragment order
  __shared__ half8 AF[16 * 64];       // 16 KB: state (rows 8..15 stay zero)
  __shared__ f32x4 RED[2 * 64];       // 2 KB : K-half partial sums

  // ---- preload Wh[h0..h0+32) as f16 fragments -----------------------------
  {
    const int lh = tid >> 3;          // 0..31 local h row
    const int k0 = (tid & 7) * 64;    // 8 threads cover K=512
    const int nt_ = lh >> 4, n_ = lh & 15;
    const float* src = Wh + (size_t)(h0 + lh) * NHID + k0;
#pragma unroll
    for (int c = 0; c < 8; c++) {
      const int k = k0 + c * 8;
      const f32x4* p = (const f32x4*)(src + c * 8);
      f32x4 lo = p[0], hi = p[1];
      half8 hb;
#pragma unroll
      for (int j = 0; j < 4; j++) { hb[j] = (_Float16)lo[j]; hb[4 + j] = (_Float16)hi[j]; }
      WhF[(nt_ * 16 + (k >> 5)) * 64 + ((k >> 3) & 3) * 16 + n_] = hb;
    }
    half8 z = {0, 0, 0, 0, 0, 0, 0, 0};
    for (int i = tid; i < 16 * 64; i += 256) AF[i] = z;  // zero => t=0 state
  }
  __syncthreads();

  const int nt = wid & 1;
  const int kh = wid >> 1;
  float bhv = 0.0f;
  if (wid < 2) bhv = bh[h0 + nt * 16 + col];
  uint32_t* const myflag = flags + wg;
  uint32_t* const gflags = flags + g * 16;

  for (int t = 0; t < T_STEPS; t++) {
    // u prefetch (independent of state; off the critical path)
    float uv[4] = {0, 0, 0, 0};
    if (wid < 2 && quad < 2) {
#pragma unroll
      for (int rr = 0; rr < 4; rr++) {
        const int row = quad * 4 + rr;
        uv[rr] = out[((size_t)(b0 + row) * T_STEPS + t) * NHID + h0 + nt * 16 + col];
      }
    }

    if (t > 0) {
      // wait until all 16 group peers have published step t-1 (relaxed:
      // atomic sc-bits route to the coherence point, no buffer_inv)
      if (tid < 16) {
        while (__hip_atomic_load(gflags + tid, __ATOMIC_RELAXED,
                                 __HIP_MEMORY_SCOPE_AGENT) < (uint32_t)t) {
          __builtin_amdgcn_s_sleep(1);
        }
      }
      __syncthreads();
      // stage state s_{t-1}[8 x 512] fp32 -> f16 fragments in AF
      const int m   = tid >> 5;          // batch row 0..7
      const int k0s = (tid & 31) * 16;   // 16 consecutive k per thread
      float* sp = out + ((size_t)(b0 + m) * T_STEPS + (t - 1)) * NHID + k0s;
      float svv[16];
#pragma unroll
      for (int i = 0; i < 16; i++)
        svv[i] = __hip_atomic_load(sp + i, __ATOMIC_RELAXED, __HIP_MEMORY_SCOPE_AGENT);
#pragma unroll
      for (int c = 0; c < 2; c++) {
        half8 hc;
#pragma unroll
        for (int j = 0; j < 8; j++) hc[j] = (_Float16)svv[c * 8 + j];
        const int k = k0s + c * 8;
        AF[(k >> 5) * 64 + ((k >> 3) & 3) * 16 + m] = hc;
      }
    }
    __syncthreads();

    // C[16x16] per wave, K half per wave pair
    f32x4 acc = {0, 0, 0, 0};
#pragma unroll
    for (int i = 0; i < 8; i++) {
      const int kk = kh * 8 + i;
      half8 a = AF[kk * 64 + lane];
      half8 b = WhF[(nt * 16 + kk) * 64 + lane];
      acc = __builtin_amdgcn_mfma_f32_16x16x32_f16(a, b, acc, 0, 0, 0);
    }
    if (kh == 1) RED[nt * 64 + lane] = acc;
    __syncthreads();

    if (wid < 2) {
      acc += RED[nt * 64 + lane];
      if (quad < 2) {  // valid batch rows 0..7
#pragma unroll
        for (int rr = 0; rr < 4; rr++) {
          const int row = quad * 4 + rr;
          const float s = uv[rr] + tanh_fast(acc[rr] + bhv);
          const size_t oi = ((size_t)(b0 + row) * T_STEPS + t) * NHID + h0 + nt * 16 + col;
          __hip_atomic_store(out + oi, s, __ATOMIC_RELAXED, __HIP_MEMORY_SCOPE_AGENT);
          if (t == T_STEPS - 1)
            out[(size_t)STATES_ELEMS + (size_t)(b0 + row) * NHID + h0 + nt * 16 + col] = s;
        }
      }
    }
    // Order: state stores complete at coherence point before flag store.
    // vmcnt(0) on the storing waves; barrier publishes to tid 0.
    asm volatile("s_waitcnt vmcnt(0)" ::: "memory");
    __syncthreads();
    if (tid == 0)
      __hip_atomic_store(myflag, (uint32_t)(t + 1), __ATOMIC_RELAXED,
                         __HIP_MEMORY_SCOPE_AGENT);
  }
}

// ---------------------------------------------------------------------------
extern "C" void kernel_launch(void* const* d_in, const int* in_sizes, int n_in,
                              void* d_out, int out_size, void* d_ws, size_t ws_size,
                              hipStream_t stream) {
  const float* x  = (const float*)d_in[0];
  const float* Wi = (const float*)d_in[1];
  const float* bi = (const float*)d_in[2];
  const float* Wh = (const float*)d_in[3];
  const float* bh = (const float*)d_in[4];
  float* out = (float*)d_out;
  uint32_t* flags = (uint32_t*)d_ws;  // 128 x u32, re-zeroed every launch

  hipLaunchKernelGGL(init_flags, dim3(1), dim3(128), 0, stream, flags);
  hipLaunchKernelGGL(phase1_gemm, dim3(1024, 8), dim3(256), 0, stream, x, Wi, bi, out);
  hipLaunchKernelGGL(phase2_scan, dim3(128), dim3(256), 0, stream, Wh, bh, out, flags);
}

// Round 3
// 3182.772 us; speedup vs baseline: 5.2867x; 1.4231x over previous
//
#include <hip/hip_runtime.h>
#include <stdint.h>

// ---------------------------------------------------------------------------
// RNN scan: out = (states[B,T,NH], last[B,NH]), fp32.
// Phase 1: u = tanh(x @ Wi^T + bi) written straight into the states region.
// Phase 2: persistent kernel; 8 batch-groups x 16 h-slice WGs. Cross-WG state
//   exchange via SELF-VALIDATING TAGGED WORDS in d_ws: word = (tag<<16)|f16.
//   One global round-trip per step: producers fire relaxed stores (no fence,
//   no flag, no vmcnt drain); consumers poll the data itself with coherent
//   dwordx4 loads. Double-buffered by t&1 (WAR-safe: publishing s_t requires
//   having consumed s_{t-1}, which implies all peers consumed s_{t-2}).
//   0xAA poison => tag 0xAAAA, never matches a real tag in [1,1024].
// ---------------------------------------------------------------------------

typedef _Float16 half8 __attribute__((ext_vector_type(8)));
typedef float    f32x4 __attribute__((ext_vector_type(4)));
typedef uint32_t u32x4 __attribute__((ext_vector_type(4)));

#define T_STEPS 1024
#define NHID    512
#define NIN     128
#define NBATCH  64
#define STATES_ELEMS (NBATCH * T_STEPS * NHID)  // 33554432

__device__ __forceinline__ float tanh_fast(float x) {
  float e = __expf(2.0f * x);
  return 1.0f - 2.0f * __builtin_amdgcn_rcpf(e + 1.0f);
}

// 4x coherent (device-scope) dwordx4 loads + single drain.
__device__ __forceinline__ void load_coherent_16(const uint32_t* p, u32x4& a,
                                                 u32x4& b, u32x4& c, u32x4& d) {
  asm volatile(
      "global_load_dwordx4 %0, %4, off sc0 sc1\n\t"
      "global_load_dwordx4 %1, %5, off sc0 sc1\n\t"
      "global_load_dwordx4 %2, %6, off sc0 sc1\n\t"
      "global_load_dwordx4 %3, %7, off sc0 sc1\n\t"
      "s_waitcnt vmcnt(0)"
      : "=v"(a), "=v"(b), "=v"(c), "=v"(d)
      : "v"(p), "v"(p + 4), "v"(p + 8), "v"(p + 12)
      : "memory");
}

// ---------------------------------------------------------------------------
// Phase 1: M=65536 (b*T+t), N=512 (h), K=128. 64x64 tile per WG.
__global__ __launch_bounds__(256) void phase1_gemm(const float* __restrict__ x,
                                                   const float* __restrict__ Wi,
                                                   const float* __restrict__ bi,
                                                   float* __restrict__ out) {
  const int tid  = threadIdx.x;
  const int wid  = tid >> 6;
  const int lane = tid & 63;
  const int quad = lane >> 4;
  const int mcol = lane & 15;
  const int r0 = blockIdx.x * 64 + wid * 16;
  const int h0 = blockIdx.y * 64;

  f32x4 acc[4] = {};
#pragma unroll
  for (int kk = 0; kk < 4; kk++) {
    const int k = kk * 32 + quad * 8;
    const f32x4* ap = (const f32x4*)(x + (size_t)(r0 + mcol) * NIN + k);
    f32x4 alo = ap[0], ahi = ap[1];
    half8 a;
#pragma unroll
    for (int j = 0; j < 4; j++) { a[j] = (_Float16)alo[j]; a[4 + j] = (_Float16)ahi[j]; }
#pragma unroll
    for (int nt = 0; nt < 4; nt++) {
      const f32x4* bp = (const f32x4*)(Wi + (size_t)(h0 + nt * 16 + mcol) * NIN + k);
      f32x4 blo = bp[0], bhi = bp[1];
      half8 b;
#pragma unroll
      for (int j = 0; j < 4; j++) { b[j] = (_Float16)blo[j]; b[4 + j] = (_Float16)bhi[j]; }
      acc[nt] = __builtin_amdgcn_mfma_f32_16x16x32_f16(a, b, acc[nt], 0, 0, 0);
    }
  }
#pragma unroll
  for (int nt = 0; nt < 4; nt++) {
    const int h = h0 + nt * 16 + mcol;
    const float bib = bi[h];
#pragma unroll
    for (int rr = 0; rr < 4; rr++) {
      const int r = r0 + quad * 4 + rr;
      out[(size_t)r * NHID + h] = tanh_fast(acc[nt][rr] + bib);
    }
  }
}

// ---------------------------------------------------------------------------
// Phase 2: persistent scan. Grid = 128 WGs x 256 threads.
//   group g = wg>>4 owns batches [8g, 8g+8); slice w = wg&15 owns h [32w,32w+32).
//   Exchange buffer (d_ws): per group 2 slots x [8 rows x 512 h] tagged dwords.
__global__ __launch_bounds__(256) void phase2_scan(const float* __restrict__ Wh,
                                                   const float* __restrict__ bh,
                                                   float* out, uint32_t* exch) {
  const int tid  = threadIdx.x;
  const int wid  = tid >> 6;
  const int lane = tid & 63;
  const int quad = lane >> 4;
  const int col  = lane & 15;
  const int wg = blockIdx.x;
  const int g  = wg >> 4;
  const int w  = wg & 15;
  const int b0 = g * 8;
  const int h0 = w * 32;

  __shared__ half8 WhF[2 * 16 * 64];  // 32 KB: Wh slice, fragment order
  __shared__ half8 AF[16 * 64];       // 16 KB: state (rows 8..15 stay zero)
  __shared__ f32x4 RED[2 * 64];       // 2 KB : K-half partial sums

  // ---- preload Wh[h0..h0+32) as f16 fragments -----------------------------
  {
    const int lh = tid >> 3;          // 0..31 local h row
    const int k0 = (tid & 7) * 64;    // 8 threads cover K=512
    const int nt_ = lh >> 4, n_ = lh & 15;
    const float* src = Wh + (size_t)(h0 + lh) * NHID + k0;
#pragma unroll
    for (int c = 0; c < 8; c++) {
      const int k = k0 + c * 8;
      const f32x4* p = (const f32x4*)(src + c * 8);
      f32x4 lo = p[0], hi = p[1];
      half8 hb;
#pragma unroll
      for (int j = 0; j < 4; j++) { hb[j] = (_Float16)lo[j]; hb[4 + j] = (_Float16)hi[j]; }
      WhF[(nt_ * 16 + (k >> 5)) * 64 + ((k >> 3) & 3) * 16 + n_] = hb;
    }
    half8 z = {0, 0, 0, 0, 0, 0, 0, 0};
    for (int i = tid; i < 16 * 64; i += 256) AF[i] = z;  // zero => t=0 state
  }
  __syncthreads();

  const int nt = wid & 1;
  const int kh = wid >> 1;
  float bhv = 0.0f;
  if (wid < 2) bhv = bh[h0 + nt * 16 + col];

  uint32_t* const exg = exch + (size_t)g * 2 * 8 * 512;  // group base
  const int m   = tid >> 5;          // consumer: batch row 0..7
  const int k0s = (tid & 31) * 16;   // consumer: 16 consecutive k

  for (int t = 0; t < T_STEPS; t++) {
    // u prefetch (independent of state; off the critical path)
    float uv[4] = {0, 0, 0, 0};
    if (wid < 2 && quad < 2) {
#pragma unroll
      for (int rr = 0; rr < 4; rr++) {
        const int row = quad * 4 + rr;
        uv[rr] = out[((size_t)(b0 + row) * T_STEPS + t) * NHID + h0 + nt * 16 + col];
      }
    }

    if (t > 0) {
      // poll tagged state words of s_{t-1} (slot (t-1)&1, tag == t)
      const uint32_t* ep = exg + ((t - 1) & 1) * (8 * 512) + m * 512 + k0s;
      const uint32_t tagv = (uint32_t)t;
      u32x4 v0, v1, v2, v3;
      for (;;) {
        load_coherent_16(ep, v0, v1, v2, v3);
        bool ready = true;
#pragma unroll
        for (int i = 0; i < 4; i++) {
          ready &= ((v0[i] >> 16) == tagv) & ((v1[i] >> 16) == tagv) &
                   ((v2[i] >> 16) == tagv) & ((v3[i] >> 16) == tagv);
        }
        if (ready) break;
        __builtin_amdgcn_s_sleep(1);
      }
      // unpack f16 payloads -> fragment-order LDS
      uint32_t vv[16] = {v0[0], v0[1], v0[2], v0[3], v1[0], v1[1], v1[2], v1[3],
                         v2[0], v2[1], v2[2], v2[3], v3[0], v3[1], v3[2], v3[3]};
#pragma unroll
      for (int c = 0; c < 2; c++) {
        half8 hc;
#pragma unroll
        for (int j = 0; j < 8; j++)
          hc[j] = __builtin_bit_cast(_Float16, (unsigned short)(vv[c * 8 + j] & 0xFFFFu));
        const int k = k0s + c * 8;
        AF[(k >> 5) * 64 + ((k >> 3) & 3) * 16 + m] = hc;
      }
    }
    __syncthreads();

    // C[16x16] per wave, K half per wave pair
    f32x4 acc = {0, 0, 0, 0};
#pragma unroll
    for (int i = 0; i < 8; i++) {
      const int kk = kh * 8 + i;
      half8 a = AF[kk * 64 + lane];
      half8 b = WhF[(nt * 16 + kk) * 64 + lane];
      acc = __builtin_amdgcn_mfma_f32_16x16x32_f16(a, b, acc, 0, 0, 0);
    }
    if (kh == 1) RED[nt * 64 + lane] = acc;
    __syncthreads();

    if (wid < 2) {
      acc += RED[nt * 64 + lane];
      if (quad < 2) {  // valid batch rows 0..7
        uint32_t* eslot = exg + (t & 1) * (8 * 512);
#pragma unroll
        for (int rr = 0; rr < 4; rr++) {
          const int row = quad * 4 + rr;
          const float s = uv[rr] + tanh_fast(acc[rr] + bhv);
          const int k = h0 + nt * 16 + col;
          // publish tagged f16 word first (critical path)...
          const uint32_t wv = ((uint32_t)(t + 1) << 16) |
                              (uint32_t)__builtin_bit_cast(unsigned short, (_Float16)s);
          __hip_atomic_store(eslot + row * 512 + k, wv, __ATOMIC_RELAXED,
                             __HIP_MEMORY_SCOPE_AGENT);
          // ...then the fp32 output (read only by the host after kernel end)
          out[((size_t)(b0 + row) * T_STEPS + t) * NHID + k] = s;
          if (t == T_STEPS - 1)
            out[(size_t)STATES_ELEMS + (size_t)(b0 + row) * NHID + k] = s;
        }
      }
    }
    // no fence, no flag, no drain — tags self-validate.
  }
}

// ---------------------------------------------------------------------------
extern "C" void kernel_launch(void* const* d_in, const int* in_sizes, int n_in,
                              void* d_out, int out_size, void* d_ws, size_t ws_size,
                              hipStream_t stream) {
  const float* x  = (const float*)d_in[0];
  const float* Wi = (const float*)d_in[1];
  const float* bi = (const float*)d_in[2];
  const float* Wh = (const float*)d_in[3];
  const float* bh = (const float*)d_in[4];
  float* out = (float*)d_out;
  uint32_t* exch = (uint32_t*)d_ws;  // 8 groups x 2 slots x 8x512 dwords = 256 KB

  hipLaunchKernelGGL(phase1_gemm, dim3(1024, 8), dim3(256), 0, stream, x, Wi, bi, out);
  hipLaunchKernelGGL(phase2_scan, dim3(128), dim3(256), 0, stream, Wh, bh, out, exch);
}